// Round 2
// 545.580 us; speedup vs baseline: 1.0165x; 1.0165x over previous
//
#include <hip/hip_runtime.h>
#include <stdint.h>

// Int8Linear: out[M][N] = fp32( (x[M][K] . W[N][K]^T) * scale[N] )
// Dtypes (confirmed): x fp32 (f16 values), W int32 in [-127,127], scale f32, out f32.
//
// Round 5 (resubmit after GPU-broker timeout; no signal to update on):
// 256x256-tile / 8-wave / double-buffered / counted-vmcnt schedule
// (T1+T3+T4+T5 port of the verified 8-phase template to i8 MFMA).
// Previous 128^2 2-barrier structure ceilinged at MfmaUtil 33% (its documented
// structural limit). This schedule: per K-tile (BK=128 B) 4 phases of
// {ds_read frags -> raw s_barrier -> lgkmcnt(0) -> setprio(1) -> 16 MFMA ->
// setprio(0) -> barrier}; prefetch distance 2 K-tiles with s_waitcnt vmcnt(8)
// (never 0 in steady state) so global_load_lds stays in flight across barriers.
// Race-freedom: stages for tile t+2 target buf (t&1) and are issued only after
// the closing barrier of tile t's compute (all waves done reading that buf);
// vmcnt(8) before tile t+1 guarantees t+1's 8 loads have landed.
// Granule-XOR LDS swizzle (16B granule, measured 0 bank conflicts) unchanged.

constexpr int Mdim = 4096, Ndim = 11008, Kdim = 4096;
constexpr int BM = 256, BN = 256, BK = 128;   // BK in int8 elements (= bytes)
constexpr int NT = Kdim / BK;                 // 32 K-tiles

typedef int i32x4 __attribute__((ext_vector_type(4)));

typedef __attribute__((address_space(1))) uint32_t gu32;
typedef __attribute__((address_space(3))) uint32_t lu32;

// ---------------- x: fp32 -> int8 per-row symmetric quant ----------------
__global__ __launch_bounds__(256) void quant_x_kernel(const float* __restrict__ x,
                                                      int8_t* __restrict__ xq,
                                                      float* __restrict__ xstep) {
    const int row = blockIdx.x;
    const int tid = threadIdx.x;
    const float* xr = x + (size_t)row * Kdim;

    float4 v[4];
    float mx = 0.f;
#pragma unroll
    for (int k = 0; k < 4; ++k) {
        v[k] = *(const float4*)(xr + k * 1024 + tid * 4);
        mx = fmaxf(mx, fmaxf(fmaxf(fabsf(v[k].x), fabsf(v[k].y)),
                             fmaxf(fabsf(v[k].z), fabsf(v[k].w))));
    }
#pragma unroll
    for (int off = 32; off; off >>= 1) mx = fmaxf(mx, __shfl_xor(mx, off, 64));
    __shared__ float red[4];
    if ((tid & 63) == 0) red[tid >> 6] = mx;
    __syncthreads();
    mx = fmaxf(fmaxf(red[0], red[1]), fmaxf(red[2], red[3]));

    const float step = fmaxf(mx, 1e-20f) / 127.f;
    const float inv  = 127.f / fmaxf(mx, 1e-20f);
    if (tid == 0) xstep[row] = step;

    int* xqi = (int*)(xq + (size_t)row * Kdim);
#pragma unroll
    for (int k = 0; k < 4; ++k) {
        int a = __float2int_rn(v[k].x * inv);
        int b = __float2int_rn(v[k].y * inv);
        int c = __float2int_rn(v[k].z * inv);
        int d = __float2int_rn(v[k].w * inv);
        xqi[(k * 1024 + tid * 4) >> 2] = (a & 255) | ((b & 255) << 8) |
                                         ((c & 255) << 16) | (d << 24);
    }
}

// ---------------- W: int32 -> int8 (exact) ----------------
__global__ __launch_bounds__(256) void cvt_w_kernel(const int* __restrict__ w,
                                                    int8_t* __restrict__ wq) {
    size_t idx = (size_t)blockIdx.x * 256 + threadIdx.x;   // 4 ints per thread
    int4 a = *(const int4*)(w + idx * 4);
    ((int*)wq)[idx] = (a.x & 255) | ((a.y & 255) << 8) | ((a.z & 255) << 16) | (a.w << 24);
}

// ---------------- GEMM: 256^2 tile, 8 waves, dbuf LDS, counted vmcnt ----------

// Stage one K-tile (A 256x128B + B 256x128B) into buffer c_.
// 8 global_load_lds issues per thread => vmcnt +8 per tile.
// Per issue: 512 threads x 16B = 64 rows; wave w writes rows [i*64+w*8, +8)
// linearly; the global source granule is pre-swizzled by (lane&7)^(row&7) so the
// linear DMA realizes the XOR-swizzled layout.
#define STAGE(c_, kt_) do {                                                          \
    _Pragma("unroll")                                                                \
    for (int i_ = 0; i_ < 4; ++i_) {                                                 \
        const int8_t* ga_ = Abase + (size_t)(i_ * 64 + srow) * Kdim + (kt_) + scol;  \
        __builtin_amdgcn_global_load_lds((gu32*)ga_,                                 \
            (lu32*)&As[c_][i_ * 64 + wave * 8][0], 16, 0, 0);                        \
    }                                                                                \
    _Pragma("unroll")                                                                \
    for (int i_ = 0; i_ < 4; ++i_) {                                                 \
        const int8_t* gw_ = Wbase + (size_t)(i_ * 64 + srow) * Kdim + (kt_) + scol;  \
        __builtin_amdgcn_global_load_lds((gu32*)gw_,                                 \
            (lu32*)&Ws[c_][i_ * 64 + wave * 8][0], 16, 0, 0);                        \
    }                                                                                \
} while (0)

// One phase: quadrant (MH_ of M-half, KS_ of K-half). 4 A-frag reads
// (+4 B-frag reads when KS_ first used), then 16 MFMAs. MH_/KS_ are literals so
// all acc[] indices are compile-time (rule #20).
#define PHASE(c_, MH_, KS_, BF_, LOADB_) do {                                        \
    const int col_ = ((KS_) ? (pgq ^ 4) : pgq) << 4;                                 \
    if (LOADB_) {                                                                    \
        _Pragma("unroll")                                                            \
        for (int ni_ = 0; ni_ < 4; ++ni_)                                            \
            BF_[ni_] = *(const i32x4*)&Ws[c_][brow0 + ni_ * 16][col_];               \
    }                                                                                \
    i32x4 af_[4];                                                                    \
    _Pragma("unroll")                                                                \
    for (int mi_ = 0; mi_ < 4; ++mi_)                                                \
        af_[mi_] = *(const i32x4*)&As[c_][arow0 + (MH_) * 64 + mi_ * 16][col_];      \
    __builtin_amdgcn_s_barrier();                                                    \
    asm volatile("s_waitcnt lgkmcnt(0)" ::: "memory");                               \
    __builtin_amdgcn_s_setprio(1);                                                   \
    _Pragma("unroll")                                                                \
    for (int mi_ = 0; mi_ < 4; ++mi_) {                                              \
        _Pragma("unroll")                                                            \
        for (int ni_ = 0; ni_ < 4; ++ni_)                                            \
            acc[(MH_) * 4 + mi_][ni_] = __builtin_amdgcn_mfma_i32_16x16x64_i8(       \
                af_[mi_], BF_[ni_], acc[(MH_) * 4 + mi_][ni_], 0, 0, 0);             \
    }                                                                                \
    __builtin_amdgcn_s_setprio(0);                                                   \
    __builtin_amdgcn_s_barrier();                                                    \
} while (0)

__global__ void __launch_bounds__(512, 2)
gemm_kernel(const int8_t* __restrict__ A,    // [M][K] int8
            const int8_t* __restrict__ W,    // [N][K] int8
            const float* __restrict__ scale, // [N]
            const float* __restrict__ xstep, // [M]
            float* __restrict__ out)         // [M][N]
{
    __shared__ __align__(16) int8_t As[2][BM][BK];  // 64 KB
    __shared__ __align__(16) int8_t Ws[2][BN][BK];  // 64 KB (total 128 KB -> 1 block/CU)

    const int tid  = threadIdx.x;
    const int wave = tid >> 6;       // 0..7
    const int lane = tid & 63;

    // XCD-bijective swizzle (688 = 8*86) then GROUP_M=8 for W-panel L2 reuse
    const int bid = blockIdx.x;
    const int wg  = (bid & 7) * 86 + (bid >> 3);
    constexpr int GM = 8, NTILE = Ndim / BN;         // 43
    const int grp = wg / (GM * NTILE);
    const int rem = wg % (GM * NTILE);
    const int m0 = (grp * GM + rem % GM) * BM;
    const int n0 = (rem / GM) * BN;

    const int wr = wave >> 2, wc = wave & 3;         // 2x4 waves, 128x64 out each
    const int frow = lane & 15, quad = lane >> 4;

    // staging addressing (pre-swizzled global source; LDS-linear DMA dest)
    const int sr   = lane >> 3;                      // 0..7
    const int sg   = (lane & 7) ^ sr;
    const int srow = wave * 8 + sr;                  // row within 64-row slab
    const int scol = sg * 16;

    const int8_t* Abase = A + (size_t)m0 * Kdim;
    const int8_t* Wbase = W + (size_t)n0 * Kdim;

    // fragment-read addressing: logical granule g of row r lives at physical
    // g^(r&7); frag granule for (ks,quad) is ks*4+quad; (q+4)^f == (q^f)^4.
    const int arow0 = wr * 128 + frow;
    const int brow0 = wc * 64 + frow;
    const int pgq   = quad ^ (frow & 7);

    i32x4 acc[8][4];
#pragma unroll
    for (int i = 0; i < 8; ++i)
#pragma unroll
        for (int j = 0; j < 4; ++j) acc[i][j] = (i32x4){0, 0, 0, 0};

    // prologue: T0 -> buf0, T1 -> buf1; wait T0 only (T1 stays in flight)
    STAGE(0, 0);
    STAGE(1, BK);
    asm volatile("s_waitcnt vmcnt(8)" ::: "memory");
    __builtin_amdgcn_s_barrier();

#pragma unroll 2
    for (int t = 0; t < NT; ++t) {
        const int c = t & 1;
        i32x4 bf0[4], bf1[4];
        PHASE(c, 0, 0, bf0, 1);
        PHASE(c, 1, 0, bf0, 0);
        PHASE(c, 0, 1, bf1, 1);
        PHASE(c, 1, 1, bf1, 0);
        // gap: all waves past the closing barrier => buf c fully consumed.
        if (t + 2 < NT) {
            STAGE(c, (t + 2) * BK);                         // T(t+2) -> buf c
            asm volatile("s_waitcnt vmcnt(8)" ::: "memory"); // T(t+1) landed
        } else {
            asm volatile("s_waitcnt vmcnt(0)" ::: "memory"); // drain tail
        }
        __builtin_amdgcn_s_barrier();
    }

    // epilogue: D layout col=frow (N), row=quad*4+r (M); dequant, fp32 store
    float sc[4];
#pragma unroll
    for (int ni = 0; ni < 4; ++ni) sc[ni] = scale[n0 + wc * 64 + ni * 16 + frow];

#pragma unroll
    for (int mh = 0; mh < 2; ++mh) {
#pragma unroll
        for (int mi = 0; mi < 4; ++mi) {
            const int mbase = m0 + wr * 128 + mh * 64 + mi * 16 + quad * 4;
            float xs4[4];
#pragma unroll
            for (int r = 0; r < 4; ++r) xs4[r] = xstep[mbase + r];
#pragma unroll
            for (int ni = 0; ni < 4; ++ni) {
                const int n = n0 + wc * 64 + ni * 16 + frow;
                float* op = out + (size_t)mbase * Ndim + n;
#pragma unroll
                for (int r = 0; r < 4; ++r)
                    op[(size_t)r * Ndim] = (float)acc[mh * 4 + mi][ni][r] * (sc[ni] * xs4[r]);
            }
        }
    }
}

// ---------------- correctness-only fallback (ws too small; never expected) ----
__global__ __launch_bounds__(256) void gemm_fallback(const float* __restrict__ A,
                                                     const int* __restrict__ W,
                                                     const float* __restrict__ scale,
                                                     float* __restrict__ out) {
    size_t o = (size_t)blockIdx.x * 256 + threadIdx.x;
    if (o >= (size_t)Mdim * Ndim) return;
    size_t m = o / Ndim, n = o % Ndim;
    float acc = 0.f;
    const float* a = A + m * Kdim;
    const int*   w = W + n * Kdim;
    for (int k = 0; k < Kdim; ++k) acc += a[k] * (float)w[k];
    out[o] = acc * scale[n];
}

extern "C" void kernel_launch(void* const* d_in, const int* in_sizes, int n_in,
                              void* d_out, int out_size, void* d_ws, size_t ws_size,
                              hipStream_t stream) {
    const float* x = (const float*)d_in[0];   // [M][K]
    const int*   w = (const int*)d_in[1];     // [N][K]
    const float* s = (const float*)d_in[2];   // [N]
    float*     out = (float*)d_out;           // [M][N]

    const size_t xN = (size_t)Mdim * Kdim;    // 16,777,216
    const size_t wN = (size_t)Ndim * Kdim;    // 45,088,768
    const size_t need = xN + wN + Mdim * sizeof(float);

    if (ws_size < need) {   // not expected (ws >= 122 MB confirmed)
        size_t total = (size_t)Mdim * Ndim;
        gemm_fallback<<<(int)((total + 255) / 256), 256, 0, stream>>>(x, w, s, out);
        return;
    }

    int8_t* xq = (int8_t*)d_ws;
    int8_t* wq = xq + xN;
    float*  xs = (float*)(wq + wN);           // 16B-aligned

    quant_x_kernel<<<Mdim, 256, 0, stream>>>(x, xq, xs);
    cvt_w_kernel<<<(int)(wN / 4 / 256), 256, 0, stream>>>(w, wq);

    dim3 grid((Mdim / BM) * (Ndim / BN)), blk(512, 1, 1);   // 688 blocks x 8 waves
    gemm_kernel<<<grid, blk, 0, stream>>>(xq, wq, s, xs, out);
}

// Round 8
// 511.689 us; speedup vs baseline: 1.0838x; 1.0662x over previous
//
#include <hip/hip_runtime.h>
#include <stdint.h>

// Int8Linear: out[M][N] = fp32( (x[M][K] . W[N][K]^T) * scale[N] )
//
// Round 7, fourth resubmit (four GPU-broker timeouts; never measured).
// 2-barrier/tile minimal-sync 256^2 tile.
// R6 post-mortem: 1 barrier/tile raced (absmax 100.5) because vmcnt is
// PER-WAVE — a top-of-tile vmcnt(8) proves only the wave's OWN loads landed,
// while it reads LDS rows DMA'd by other waves. Correct minimum is 2 barriers:
//   compute tile t from buf c (free-scheduled ds_reads+MFMA, no internal sync)
//   lgkmcnt(0)                 // own reads of buf c complete
//   s_barrier  (A)             // ALL waves' reads of buf c complete
//   STAGE(t+2) -> buf c        // DMA-overwrite now safe
//   vmcnt(8)                   // own t+1 loads landed (issued 1 tile ago,
//                              // ~3.5k cyc slack >> ~900 cyc HBM latency => ~free)
//   s_barrier  (B)             // ALL waves' t+1 loads landed -> next reads safe
// vs R5's 9 barriers/tile (6803 cyc/tile wall, 2611 cyc MFMA need, 38% util).
// Granule-XOR LDS swizzle (0 measured conflicts) and 256^2/8-wave geometry kept.

constexpr int Mdim = 4096, Ndim = 11008, Kdim = 4096;
constexpr int BM = 256, BN = 256, BK = 128;   // BK in int8 elements (= bytes)
constexpr int NT = Kdim / BK;                 // 32 K-tiles

typedef int i32x4 __attribute__((ext_vector_type(4)));

typedef __attribute__((address_space(1))) uint32_t gu32;
typedef __attribute__((address_space(3))) uint32_t lu32;

// ---------------- x: fp32 -> int8 per-row symmetric quant ----------------
__global__ __launch_bounds__(256) void quant_x_kernel(const float* __restrict__ x,
                                                      int8_t* __restrict__ xq,
                                                      float* __restrict__ xstep) {
    const int row = blockIdx.x;
    const int tid = threadIdx.x;
    const float* xr = x + (size_t)row * Kdim;

    float4 v[4];
    float mx = 0.f;
#pragma unroll
    for (int k = 0; k < 4; ++k) {
        v[k] = *(const float4*)(xr + k * 1024 + tid * 4);
        mx = fmaxf(mx, fmaxf(fmaxf(fabsf(v[k].x), fabsf(v[k].y)),
                             fmaxf(fabsf(v[k].z), fabsf(v[k].w))));
    }
#pragma unroll
    for (int off = 32; off; off >>= 1) mx = fmaxf(mx, __shfl_xor(mx, off, 64));
    __shared__ float red[4];
    if ((tid & 63) == 0) red[tid >> 6] = mx;
    __syncthreads();
    mx = fmaxf(fmaxf(red[0], red[1]), fmaxf(red[2], red[3]));

    const float step = fmaxf(mx, 1e-20f) / 127.f;
    const float inv  = 127.f / fmaxf(mx, 1e-20f);
    if (tid == 0) xstep[row] = step;

    int* xqi = (int*)(xq + (size_t)row * Kdim);
#pragma unroll
    for (int k = 0; k < 4; ++k) {
        int a = __float2int_rn(v[k].x * inv);
        int b = __float2int_rn(v[k].y * inv);
        int c = __float2int_rn(v[k].z * inv);
        int d = __float2int_rn(v[k].w * inv);
        xqi[(k * 1024 + tid * 4) >> 2] = (a & 255) | ((b & 255) << 8) |
                                         ((c & 255) << 16) | (d << 24);
    }
}

// ---------------- W: int32 -> int8 (exact) ----------------
__global__ __launch_bounds__(256) void cvt_w_kernel(const int* __restrict__ w,
                                                    int8_t* __restrict__ wq) {
    size_t idx = (size_t)blockIdx.x * 256 + threadIdx.x;   // 4 ints per thread
    int4 a = *(const int4*)(w + idx * 4);
    ((int*)wq)[idx] = (a.x & 255) | ((a.y & 255) << 8) | ((a.z & 255) << 16) | (a.w << 24);
}

// ---------------- GEMM: 256^2 tile, 8 waves, dbuf LDS, 2 barriers/tile -------

// Stage one K-tile (A 256x128B + B 256x128B) into buffer c_.
// 8 global_load_lds issues per thread => vmcnt +8 per tile.
#define STAGE(c_, kt_) do {                                                          \
    _Pragma("unroll")                                                                \
    for (int i_ = 0; i_ < 4; ++i_) {                                                 \
        const int8_t* ga_ = Abase + (size_t)(i_ * 64 + srow) * Kdim + (kt_) + scol;  \
        __builtin_amdgcn_global_load_lds((gu32*)ga_,                                 \
            (lu32*)&As[c_][i_ * 64 + wave * 8][0], 16, 0, 0);                        \
    }                                                                                \
    _Pragma("unroll")                                                                \
    for (int i_ = 0; i_ < 4; ++i_) {                                                 \
        const int8_t* gw_ = Wbase + (size_t)(i_ * 64 + srow) * Kdim + (kt_) + scol;  \
        __builtin_amdgcn_global_load_lds((gu32*)gw_,                                 \
            (lu32*)&Ws[c_][i_ * 64 + wave * 8][0], 16, 0, 0);                        \
    }                                                                                \
} while (0)

// One compute quadrant, NO sync: 4 A-frag ds_reads (+4 B-frag on first use of a
// K-half), 16 MFMAs. MH_/KS_ literals so acc indices are compile-time (rule #20).
#define QUAD(c_, MH_, KS_, BF_, LOADB_) do {                                         \
    const int col_ = ((KS_) ? (pgq ^ 4) : pgq) << 4;                                 \
    if (LOADB_) {                                                                    \
        _Pragma("unroll")                                                            \
        for (int ni_ = 0; ni_ < 4; ++ni_)                                            \
            BF_[ni_] = *(const i32x4*)&Ws[c_][brow0 + ni_ * 16][col_];               \
    }                                                                                \
    i32x4 af_[4];                                                                    \
    _Pragma("unroll")                                                                \
    for (int mi_ = 0; mi_ < 4; ++mi_)                                                \
        af_[mi_] = *(const i32x4*)&As[c_][arow0 + (MH_) * 64 + mi_ * 16][col_];      \
    _Pragma("unroll")                                                                \
    for (int mi_ = 0; mi_ < 4; ++mi_) {                                              \
        _Pragma("unroll")                                                            \
        for (int ni_ = 0; ni_ < 4; ++ni_)                                            \
            acc[(MH_) * 4 + mi_][ni_] = __builtin_amdgcn_mfma_i32_16x16x64_i8(       \
                af_[mi_], BF_[ni_], acc[(MH_) * 4 + mi_][ni_], 0, 0, 0);             \
    }                                                                                \
} while (0)

__global__ void __launch_bounds__(512, 2)
gemm_kernel(const int8_t* __restrict__ A,    // [M][K] int8
            const int8_t* __restrict__ W,    // [N][K] int8
            const float* __restrict__ scale, // [N]
            const float* __restrict__ xstep, // [M]
            float* __restrict__ out)         // [M][N]
{
    __shared__ __align__(16) int8_t As[2][BM][BK];  // 64 KB
    __shared__ __align__(16) int8_t Ws[2][BN][BK];  // 64 KB

    const int tid  = threadIdx.x;
    const int wave = tid >> 6;       // 0..7
    const int lane = tid & 63;

    // XCD-bijective swizzle (688 = 8*86) then GROUP_M=8 for W-panel L2 reuse
    const int bid = blockIdx.x;
    const int wg  = (bid & 7) * 86 + (bid >> 3);
    constexpr int GM = 8, NTILE = Ndim / BN;         // 43
    const int grp = wg / (GM * NTILE);
    const int rem = wg % (GM * NTILE);
    const int m0 = (grp * GM + rem % GM) * BM;
    const int n0 = (rem / GM) * BN;

    const int wr = wave >> 2, wc = wave & 3;         // 2x4 waves, 128x64 out each
    const int frow = lane & 15, quad = lane >> 4;

    // staging addressing (pre-swizzled global source; LDS-linear DMA dest)
    const int sr   = lane >> 3;                      // 0..7
    const int sg   = (lane & 7) ^ sr;
    const int srow = wave * 8 + sr;                  // row within 64-row slab
    const int scol = sg * 16;

    const int8_t* Abase = A + (size_t)m0 * Kdim;
    const int8_t* Wbase = W + (size_t)n0 * Kdim;

    // fragment-read addressing: logical granule g of row r lives at physical
    // g^(r&7); frag granule for (ks,quad) is ks*4+quad; (q+4)^f == (q^f)^4.
    const int arow0 = wr * 128 + frow;
    const int brow0 = wc * 64 + frow;
    const int pgq   = quad ^ (frow & 7);

    i32x4 acc[8][4];
#pragma unroll
    for (int i = 0; i < 8; ++i)
#pragma unroll
        for (int j = 0; j < 4; ++j) acc[i][j] = (i32x4){0, 0, 0, 0};

    // prologue: T0 -> buf0, T1 -> buf1; own-T0 vmcnt + barrier publishes T0
    // block-wide (T1's 8 loads stay in flight).
    STAGE(0, 0);
    STAGE(1, BK);
    asm volatile("s_waitcnt vmcnt(8)" ::: "memory");
    __builtin_amdgcn_s_barrier();

#pragma unroll 2
    for (int t = 0; t < NT; ++t) {
        const int c = t & 1;

        i32x4 bf0[4], bf1[4];
        QUAD(c, 0, 0, bf0, 1);
        QUAD(c, 1, 0, bf0, 0);
        QUAD(c, 0, 1, bf1, 1);
        QUAD(c, 1, 1, bf1, 0);

        if (t + 1 < NT) {
            // (A) all waves done READING buf c -> safe to DMA-overwrite it
            asm volatile("s_waitcnt lgkmcnt(0)" ::: "memory");
            __builtin_amdgcn_s_barrier();
            if (t + 2 < NT) {
                STAGE(c, (t + 2) * BK);                          // T(t+2) -> buf c
                asm volatile("s_waitcnt vmcnt(8)" ::: "memory"); // own T(t+1) landed
            } else {
                asm volatile("s_waitcnt vmcnt(0)" ::: "memory"); // tail drain
            }
            // (B) all waves' T(t+1) loads landed -> next tile's reads are safe
            __builtin_amdgcn_s_barrier();
        }
    }

    // epilogue: D layout col=frow (N), row=quad*4+r (M); dequant, fp32 store
    float sc[4];
#pragma unroll
    for (int ni = 0; ni < 4; ++ni) sc[ni] = scale[n0 + wc * 64 + ni * 16 + frow];

#pragma unroll
    for (int mh = 0; mh < 2; ++mh) {
#pragma unroll
        for (int mi = 0; mi < 4; ++mi) {
            const int mbase = m0 + wr * 128 + mh * 64 + mi * 16 + quad * 4;
            float xs4[4];
#pragma unroll
            for (int r = 0; r < 4; ++r) xs4[r] = xstep[mbase + r];
#pragma unroll
            for (int ni = 0; ni < 4; ++ni) {
                const int n = n0 + wc * 64 + ni * 16 + frow;
                float* op = out + (size_t)mbase * Ndim + n;
#pragma unroll
                for (int r = 0; r < 4; ++r)
                    op[(size_t)r * Ndim] = (float)acc[mh * 4 + mi][ni][r] * (sc[ni] * xs4[r]);
            }
        }
    }
}

// ---------------- correctness-only fallback (ws too small; never expected) ----
__global__ __launch_bounds__(256) void gemm_fallback(const float* __restrict__ A,
                                                     const int* __restrict__ W,
                                                     const float* __restrict__ scale,
                                                     float* __restrict__ out) {
    size_t o = (size_t)blockIdx.x * 256 + threadIdx.x;
    if (o >= (size_t)Mdim * Ndim) return;
    size_t m = o / Ndim, n = o % Ndim;
    float acc = 0.f;
    const float* a = A + m * Kdim;
    const int*   w = W + n * Kdim;
    for (int k = 0; k < Kdim; ++k) acc += a[k] * (float)w[k];
    out[o] = acc * scale[n];
}

extern "C" void kernel_launch(void* const* d_in, const int* in_sizes, int n_in,
                              void* d_out, int out_size, void* d_ws, size_t ws_size,
                              hipStream_t stream) {
    const float* x = (const float*)d_in[0];   // [M][K]
    const int*   w = (const int*)d_in[1];     // [N][K]
    const float* s = (const float*)d_in[2];   // [N]
    float*     out = (float*)d_out;           // [M][N]

    const size_t xN = (size_t)Mdim * Kdim;    // 16,777,216
    const size_t wN = (size_t)Ndim * Kdim;    // 45,088,768
    const size_t need = xN + wN + Mdim * sizeof(float);

    if (ws_size < need) {   // not expected (ws >= 122 MB confirmed)
        size_t total = (size_t)Mdim * Ndim;
        gemm_fallback<<<(int)((total + 255) / 256), 256, 0, stream>>>(x, w, s, out);
        return;
    }

    int8_t* xq = (int8_t*)d_ws;
    int8_t* wq = xq + xN;
    float*  xs = (float*)(wq + wN);           // 16B-aligned

    quant_x_kernel<<<Mdim, 256, 0, stream>>>(x, xq, xs);
    cvt_w_kernel<<<(int)(wN / 4 / 256), 256, 0, stream>>>(w, wq);

    dim3 grid((Mdim / BM) * (Ndim / BN)), blk(512, 1, 1);   // 688 blocks x 8 waves
    gemm_kernel<<<grid, blk, 0, stream>>>(xq, wq, s, xs, out);
}

// Round 13
// 500.698 us; speedup vs baseline: 1.1076x; 1.0219x over previous
//
#include <hip/hip_runtime.h>
#include <stdint.h>

// Int8Linear: out[M][N] = fp32( (x[M][K] . W[N][K]^T) * scale[N] )
//
// Round 8, fourth resubmit (GPU-broker timeouts; never measured).
// asm-ds_read K-loop. R7 post-mortem: removing barriers (9->2/tile)
// gained only 10% (220 µs, MfmaUtil 36%) — per-tile wall 6141 cyc vs 2611 MFMA
// need, with LDS reads + DMA writes + MFMA all SERIAL. Theory: the compiler's
// waitcnt legalizer cannot credit our asm vmcnt(8); at every C++ ds_read of a
// buffer with an outstanding global_load_lds DMA to the SAME object it inserts
// its own conservative drain -> prefetch depth 0, each tile pays full staging
// latency. Fix: all LDS fragment reads are inline-asm ds_read_b128 (opaque to
// the legalizer; completion governed by counted lgkmcnt + sched_barrier(0),
// rule #18). Barriers are asm s_barrier with "memory" clobber so STAGE cannot
// hoist across (DSRs are opaque -> alias analysis no longer orders them).
// Per K-half: 12 DSR -> lgkmcnt(4) -> 16 MFMA (MH0) -> lgkmcnt(0) -> 16 MFMA
// (MH1), setprio(1) around clusters. Sync protocol, swizzle, and geometry are
// byte-identical to R7 (which passed). quant_x+cvt_w fused into one dispatch.

constexpr int Mdim = 4096, Ndim = 11008, Kdim = 4096;
constexpr int BM = 256, BN = 256, BK = 128;   // BK in int8 elements (= bytes)
constexpr int NT = Kdim / BK;                 // 32 K-tiles

typedef int i32x4 __attribute__((ext_vector_type(4)));

typedef __attribute__((address_space(1))) uint32_t gu32;
typedef __attribute__((address_space(3))) uint32_t lu32;

// ---------------- fused prep: x fp32->int8 rowquant  +  W int32->int8 --------
__global__ __launch_bounds__(256) void prep_kernel(const float* __restrict__ x,
                                                   int8_t* __restrict__ xq,
                                                   float* __restrict__ xstep,
                                                   const int* __restrict__ w,
                                                   int8_t* __restrict__ wq) {
    const int tid = threadIdx.x;
    if (blockIdx.x < Mdim) {                       // ---- quant_x branch ----
        const int row = blockIdx.x;
        const float* xr = x + (size_t)row * Kdim;

        float4 v[4];
        float mx = 0.f;
#pragma unroll
        for (int k = 0; k < 4; ++k) {
            v[k] = *(const float4*)(xr + k * 1024 + tid * 4);
            mx = fmaxf(mx, fmaxf(fmaxf(fabsf(v[k].x), fabsf(v[k].y)),
                                 fmaxf(fabsf(v[k].z), fabsf(v[k].w))));
        }
#pragma unroll
        for (int off = 32; off; off >>= 1) mx = fmaxf(mx, __shfl_xor(mx, off, 64));
        __shared__ float red[4];
        if ((tid & 63) == 0) red[tid >> 6] = mx;
        __syncthreads();
        mx = fmaxf(fmaxf(red[0], red[1]), fmaxf(red[2], red[3]));

        const float step = fmaxf(mx, 1e-20f) / 127.f;
        const float inv  = 127.f / fmaxf(mx, 1e-20f);
        if (tid == 0) xstep[row] = step;

        int* xqi = (int*)(xq + (size_t)row * Kdim);
#pragma unroll
        for (int k = 0; k < 4; ++k) {
            int a = __float2int_rn(v[k].x * inv);
            int b = __float2int_rn(v[k].y * inv);
            int c = __float2int_rn(v[k].z * inv);
            int d = __float2int_rn(v[k].w * inv);
            xqi[(k * 1024 + tid * 4) >> 2] = (a & 255) | ((b & 255) << 8) |
                                             ((c & 255) << 16) | (d << 24);
        }
    } else {                                       // ---- cvt_w branch ----
        size_t idx = (size_t)(blockIdx.x - Mdim) * 256 + tid;   // 4 ints/thread
        int4 a = *(const int4*)(w + idx * 4);
        ((int*)wq)[idx] = (a.x & 255) | ((a.y & 255) << 8) |
                          ((a.z & 255) << 16) | (a.w << 24);
    }
}

// ---------------- GEMM: 256^2, 8 waves, dbuf LDS, asm reads, 2 barriers/tile --

// opaque LDS read: legalizer inserts no waits; we own completion via lgkmcnt.
#define DSR(d_, a_, OFF_) \
    asm volatile("ds_read_b128 %0, %1 offset:" OFF_ : "=v"(d_) : "v"(a_))

// Stage one K-tile (A 256x128B + B 256x128B) into buffer c_ (runtime ok).
// 8 global_load_lds issues per thread => vmcnt +8 per tile.
#define STAGE(c_, kt_) do {                                                          \
    _Pragma("unroll")                                                                \
    for (int i_ = 0; i_ < 4; ++i_) {                                                 \
        const int8_t* ga_ = Abase + (size_t)(i_ * 64 + srow) * Kdim + (kt_) + scol;  \
        __builtin_amdgcn_global_load_lds((gu32*)ga_,                                 \
            (lu32*)&As[c_][i_ * 64 + wave * 8][0], 16, 0, 0);                        \
    }                                                                                \
    _Pragma("unroll")                                                                \
    for (int i_ = 0; i_ < 4; ++i_) {                                                 \
        const int8_t* gw_ = Wbase + (size_t)(i_ * 64 + srow) * Kdim + (kt_) + scol;  \
        __builtin_amdgcn_global_load_lds((gu32*)gw_,                                 \
            (lu32*)&Ws[c_][i_ * 64 + wave * 8][0], 16, 0, 0);                        \
    }                                                                                \
} while (0)

// One K-half (K=64): 12 asm ds_read_b128 (4 B + 4 A-MH0 + 4 A-MH1), then
// lgkmcnt(4) -> 16 MFMA on MH0, lgkmcnt(0) -> 16 MFMA on MH1.
// rule #18: sched_barrier(0) after each lgkmcnt so MFMAs can't hoist above it.
#define KHALF(aAddr_, bAddr_) do {                                                   \
    i32x4 bf_[4], af0_[4], af1_[4];                                                  \
    DSR(bf_[0],  bAddr_, "0");     DSR(bf_[1],  bAddr_, "2048");                     \
    DSR(bf_[2],  bAddr_, "4096");  DSR(bf_[3],  bAddr_, "6144");                     \
    DSR(af0_[0], aAddr_, "0");     DSR(af0_[1], aAddr_, "2048");                     \
    DSR(af0_[2], aAddr_, "4096");  DSR(af0_[3], aAddr_, "6144");                     \
    DSR(af1_[0], aAddr_, "8192");  DSR(af1_[1], aAddr_, "10240");                    \
    DSR(af1_[2], aAddr_, "12288"); DSR(af1_[3], aAddr_, "14336");                    \
    asm volatile("s_waitcnt lgkmcnt(4)");                                            \
    __builtin_amdgcn_sched_barrier(0);                                               \
    __builtin_amdgcn_s_setprio(1);                                                   \
    _Pragma("unroll")                                                                \
    for (int mi_ = 0; mi_ < 4; ++mi_) {                                              \
        _Pragma("unroll")                                                            \
        for (int ni_ = 0; ni_ < 4; ++ni_)                                            \
            acc[mi_][ni_] = __builtin_amdgcn_mfma_i32_16x16x64_i8(                   \
                af0_[mi_], bf_[ni_], acc[mi_][ni_], 0, 0, 0);                        \
    }                                                                                \
    __builtin_amdgcn_s_setprio(0);                                                   \
    asm volatile("s_waitcnt lgkmcnt(0)");                                            \
    __builtin_amdgcn_sched_barrier(0);                                               \
    __builtin_amdgcn_s_setprio(1);                                                   \
    _Pragma("unroll")                                                                \
    for (int mi_ = 0; mi_ < 4; ++mi_) {                                              \
        _Pragma("unroll")                                                            \
        for (int ni_ = 0; ni_ < 4; ++ni_)                                            \
            acc[4 + mi_][ni_] = __builtin_amdgcn_mfma_i32_16x16x64_i8(               \
                af1_[mi_], bf_[ni_], acc[4 + mi_][ni_], 0, 0, 0);                    \
    }                                                                                \
    __builtin_amdgcn_s_setprio(0);                                                   \
} while (0)

__global__ void __launch_bounds__(512, 2)
gemm_kernel(const int8_t* __restrict__ A,    // [M][K] int8
            const int8_t* __restrict__ W,    // [N][K] int8
            const float* __restrict__ scale, // [N]
            const float* __restrict__ xstep, // [M]
            float* __restrict__ out)         // [M][N]
{
    __shared__ __align__(16) int8_t As[2][BM][BK];  // 64 KB
    __shared__ __align__(16) int8_t Ws[2][BN][BK];  // 64 KB

    const int tid  = threadIdx.x;
    const int wave = tid >> 6;       // 0..7
    const int lane = tid & 63;

    // XCD-bijective swizzle (688 = 8*86) then GROUP_M=8 for W-panel L2 reuse
    const int bid = blockIdx.x;
    const int wg  = (bid & 7) * 86 + (bid >> 3);
    constexpr int GM = 8, NTILE = Ndim / BN;         // 43
    const int grp = wg / (GM * NTILE);
    const int rem = wg % (GM * NTILE);
    const int m0 = (grp * GM + rem % GM) * BM;
    const int n0 = (rem / GM) * BN;

    const int wr = wave >> 2, wc = wave & 3;         // 2x4 waves, 128x64 out each
    const int frow = lane & 15, quad = lane >> 4;

    // staging addressing (pre-swizzled global source; LDS-linear DMA dest)
    const int sr   = lane >> 3;                      // 0..7
    const int sg   = (lane & 7) ^ sr;
    const int srow = wave * 8 + sr;                  // row within 64-row slab
    const int scol = sg * 16;

    const int8_t* Abase = A + (size_t)m0 * Kdim;
    const int8_t* Wbase = W + (size_t)n0 * Kdim;

    // fragment-read addressing: logical granule g of row r lives at physical
    // g^(r&7); KH0 granule = quad -> col0 = (quad^(frow&7))<<4; KH1 flips bit 6.
    const int arow0 = wr * 128 + frow;
    const int brow0 = wc * 64 + frow;
    const int pgq   = quad ^ (frow & 7);
    const uint32_t col0  = (uint32_t)(pgq << 4);
    const uint32_t aBase = (uint32_t)(uintptr_t)&As[0][0][0] + (uint32_t)(arow0 * BK) + col0;
    const uint32_t bBase = (uint32_t)(uintptr_t)&Ws[0][0][0] + (uint32_t)(brow0 * BK) + col0;

    i32x4 acc[8][4];
#pragma unroll
    for (int i = 0; i < 8; ++i)
#pragma unroll
        for (int j = 0; j < 4; ++j) acc[i][j] = (i32x4){0, 0, 0, 0};

    // prologue: T0 -> buf0, T1 -> buf1; own-T0 vmcnt + barrier publishes T0
    // block-wide (T1's 8 loads stay in flight).
    STAGE(0, 0);
    STAGE(1, BK);
    asm volatile("s_waitcnt vmcnt(8)" ::: "memory");
    asm volatile("s_barrier" ::: "memory");

#pragma unroll 2
    for (int t = 0; t < NT; ++t) {
        const uint32_t boff = (uint32_t)((t & 1) * (BM * BK));
        const uint32_t aA = aBase + boff, bA = bBase + boff;

        KHALF(aA, bA);                 // K-half 0 (cols granules 0..3)
        KHALF(aA ^ 64u, bA ^ 64u);     // K-half 1 (granules 4..7)

        if (t + 1 < NT) {
            // (A) all waves done READING buf c (lgkmcnt(0) inside KHALF) ->
            //     safe to DMA-overwrite it. "memory" keeps STAGE below.
            asm volatile("s_barrier" ::: "memory");
            if (t + 2 < NT) {
                STAGE(t & 1, (t + 2) * BK);                      // T(t+2) -> buf c
                asm volatile("s_waitcnt vmcnt(8)" ::: "memory"); // own T(t+1) landed
            } else {
                asm volatile("s_waitcnt vmcnt(0)" ::: "memory"); // tail drain
            }
            // (B) all waves' T(t+1) loads landed -> next tile's reads are safe
            asm volatile("s_barrier" ::: "memory");
        }
    }

    // epilogue: D layout col=frow (N), row=quad*4+r (M); dequant, fp32 store
    float sc[4];
#pragma unroll
    for (int ni = 0; ni < 4; ++ni) sc[ni] = scale[n0 + wc * 64 + ni * 16 + frow];

#pragma unroll
    for (int mh = 0; mh < 2; ++mh) {
#pragma unroll
        for (int mi = 0; mi < 4; ++mi) {
            const int mbase = m0 + wr * 128 + mh * 64 + mi * 16 + quad * 4;
            float xs4[4];
#pragma unroll
            for (int r = 0; r < 4; ++r) xs4[r] = xstep[mbase + r];
#pragma unroll
            for (int ni = 0; ni < 4; ++ni) {
                const int n = n0 + wc * 64 + ni * 16 + frow;
                float* op = out + (size_t)mbase * Ndim + n;
#pragma unroll
                for (int r = 0; r < 4; ++r)
                    op[(size_t)r * Ndim] = (float)acc[mh * 4 + mi][ni][r] * (sc[ni] * xs4[r]);
            }
        }
    }
}

// ---------------- correctness-only fallback (ws too small; never expected) ----
__global__ __launch_bounds__(256) void gemm_fallback(const float* __restrict__ A,
                                                     const int* __restrict__ W,
                                                     const float* __restrict__ scale,
                                                     float* __restrict__ out) {
    size_t o = (size_t)blockIdx.x * 256 + threadIdx.x;
    if (o >= (size_t)Mdim * Ndim) return;
    size_t m = o / Ndim, n = o % Ndim;
    float acc = 0.f;
    const float* a = A + m * Kdim;
    const int*   w = W + n * Kdim;
    for (int k = 0; k < Kdim; ++k) acc += a[k] * (float)w[k];
    out[o] = acc * scale[n];
}

extern "C" void kernel_launch(void* const* d_in, const int* in_sizes, int n_in,
                              void* d_out, int out_size, void* d_ws, size_t ws_size,
                              hipStream_t stream) {
    const float* x = (const float*)d_in[0];   // [M][K]
    const int*   w = (const int*)d_in[1];     // [N][K]
    const float* s = (const float*)d_in[2];   // [N]
    float*     out = (float*)d_out;           // [M][N]

    const size_t xN = (size_t)Mdim * Kdim;    // 16,777,216
    const size_t wN = (size_t)Ndim * Kdim;    // 45,088,768
    const size_t need = xN + wN + Mdim * sizeof(float);

    if (ws_size < need) {   // not expected (ws >= 122 MB confirmed)
        size_t total = (size_t)Mdim * Ndim;
        gemm_fallback<<<(int)((total + 255) / 256), 256, 0, stream>>>(x, w, s, out);
        return;
    }

    int8_t* xq = (int8_t*)d_ws;
    int8_t* wq = xq + xN;
    float*  xs = (float*)(wq + wN);           // 16B-aligned

    const int cvtBlocks = (int)(wN / 4 / 256);            // 44032
    prep_kernel<<<Mdim + cvtBlocks, 256, 0, stream>>>(x, xq, xs, w, wq);

    dim3 grid((Mdim / BM) * (Ndim / BN)), blk(512, 1, 1);   // 688 blocks x 8 waves
    gemm_kernel<<<grid, blk, 0, stream>>>(xq, wq, s, xs, out);
}